// Round 2
// baseline (170.404 us; speedup 1.0000x reference)
//
#include <hip/hip_runtime.h>
#include <hip/hip_fp16.h>

// CIN (xDeepFM), B=4096, F=32, D=64, layers 128/128.
// Per row m=(b,d): t = x[b,:,d] (32 f32)
//   layer0: y0[o] = relu(b0[o] + sum_{h,f} w0[o, h*32+f] t[h] t[f])
//   hidden = y0[0:64]; direct0 = y0[64:128]
//   layer1: y1[o] = relu(b1[o] + sum_{hh,f} w1[o, hh*32+f] hidden[hh] t[f])
//   out[b] = concat(direct0, y1) summed over d  -> (4096, 192) f32
//
// MFMA mapping (v_mfma_f32_16x16x32_f16):
//   A frag: lane holds A[m = l&15][k = (l>>4)*8 + j]
//   B frag: lane holds B[k = (l>>4)*8 + j][n = l&15]
//   C/D   : col = l&15, row = (l>>4)*4 + reg
//
// Round-11: R10's register pipeline was NEUTRAL -> iter-start read latency
// is NOT the bubble. Revised theory: __syncthreads() drains vmcnt(0)
// every iter; the newest global_load_lds is always issued in the SAME
// iter, so the drain eats (loaded-L2-latency - burst) each iter no matter
// how deep the register pipeline is (T3-without-T4). Fix: 3-deep LDS
// staging (slot = k%3) + raw s_barrier with COUNTED vmcnt(2): each
// barrier drains only stage(k+2) (needed next iter) and leaves stage(k+3)
// in flight, giving each stage ~1.7 iters of slack. Only Wb is
// cross-wave (Xh/Hsm wave-private) so vmcnt(2)+lgkmcnt(0) suffices.
// Plus s_setprio(1) around the MFMA burst (T5: pays only with counted
// schedules, m218b).

typedef __attribute__((ext_vector_type(8))) _Float16 f16x8;
typedef __attribute__((ext_vector_type(4))) float f32x4;
typedef __attribute__((ext_vector_type(4))) unsigned short us4;
typedef unsigned short ushortT;

#define BAR_VM2() asm volatile("s_waitcnt vmcnt(2) lgkmcnt(0)\n\ts_barrier" ::: "memory")
#define BAR_VM4() asm volatile("s_waitcnt vmcnt(4) lgkmcnt(0)\n\ts_barrier" ::: "memory")

// ---------- weight pre-pack: f32 -> f16 in B-fragment order ----------
// Stream chunk ktg (8192 B = 4096 ushorts): frag (ktg, n) at ushort
// offset ktg*4096 + n*512 + l*8.
// ktg<32 -> w0 kt=ktg; ktg>=32 -> w1 kt=ktg-32 (contiguous: 32*4096=131072).
__global__ void cin_pack_w(const float* __restrict__ w0,
                           const float* __restrict__ w1,
                           ushortT* __restrict__ wp) {
    int gidx = blockIdx.x * 256 + threadIdx.x;
    if (gidx >= 49152) return;
    const float* src;
    ushortT* dst;
    if (gidx < 16384) {
        int kk = gidx >> 9, rem = gidx & 511;
        int n = rem >> 6, lp = rem & 63;
        int o = n * 16 + (lp & 15);
        int c = kk * 32 + ((lp >> 4) << 3);
        src = w0 + o * 1024 + c;
        dst = wp + gidx * 8;
    } else {
        int g1 = gidx - 16384;
        int kk = g1 >> 9, rem = g1 & 511;
        int n = rem >> 6, lp = rem & 63;
        int o = n * 16 + (lp & 15);
        int c = kk * 32 + ((lp >> 4) << 3);
        src = w1 + o * 2048 + c;
        dst = wp + 131072 + g1 * 8;
    }
    ushortT tmp[8];
#pragma unroll
    for (int j = 0; j < 8; ++j) {
        __half h = __float2half(src[j]);
        tmp[j] = __builtin_bit_cast(ushortT, h);
    }
    *reinterpret_cast<f16x8*>(dst) = *reinterpret_cast<const f16x8*>(tmp);
}

__global__ __launch_bounds__(256, 2) void cin_mfma_kernel(
    const float* __restrict__ x,      // [4096][32][64]
    const float* __restrict__ b0,     // [128]
    const float* __restrict__ b1,     // [128]
    const ushortT* __restrict__ wp,   // packed weights (f16 bits)
    float* __restrict__ out)          // [4096][192]
{
    const int tid = threadIdx.x;
    const int l   = tid & 63;         // lane
    const int w   = tid >> 6;         // wave 0..3 -> b = blockIdx*4 + w
    const int b   = blockIdx.x * 4 + w;
    const int r16 = l & 15;
    const int g   = l >> 4;

    __shared__ ushortT Xh[4][2048];                   // f16 x[f][d] per wave (16 KB)
    __shared__ ushortT Hsm[4][64 * 66];               // f16 hidden per wave (33 KB)
    __shared__ __align__(16) ushortT Wb[3][4096];     // weight 3-slot ring (24 KB)

    ushortT* Xw = Xh[w];
    ushortT* Hw = Hsm[w];

    // ---- prologue: x (f32) -> f16 table Xw (own wave) ----
    const float* xb = x + (size_t)b * 2048;
#pragma unroll
    for (int i = 0; i < 8; ++i) {
        float4 v = reinterpret_cast<const float4*>(xb)[i * 64 + l];
        int flat = (i * 64 + l) * 4;
        us4 h;
        h[0] = __builtin_bit_cast(ushortT, __float2half(v.x));
        h[1] = __builtin_bit_cast(ushortT, __float2half(v.y));
        h[2] = __builtin_bit_cast(ushortT, __float2half(v.z));
        h[3] = __builtin_bit_cast(ushortT, __float2half(v.w));
        *reinterpret_cast<us4*>(&Xw[flat]) = h;
    }

    // ---- stage chunks 0,1,2 into slots 0,1,2 (2 x 1 KB per wave each) ----
#pragma unroll
    for (int c = 0; c < 3; ++c) {
        const char* src = (const char*)wp + (size_t)c * 8192 +
                          (size_t)(w * 2) * 1024 + (size_t)l * 16;
        __builtin_amdgcn_global_load_lds((const unsigned int*)src,
                                         (unsigned int*)&Wb[c][(w * 2) * 512], 16, 0, 0);
        __builtin_amdgcn_global_load_lds((const unsigned int*)(src + 1024),
                                         (unsigned int*)&Wb[c][(w * 2 + 1) * 512], 16, 0, 0);
    }
    // stage(0) drained (own 2 oldest), slot 0 published; stages 1,2 in flight
    BAR_VM4();

    // ---- base T-fragments: tf16[mt][p] = (t[d][g*8+2p], t[d][g*8+2p+1]) ----
    __half2 tf16[4][4];
#pragma unroll
    for (int mt = 0; mt < 4; ++mt)
#pragma unroll
        for (int p = 0; p < 4; ++p) {
            unsigned lo = Xw[(g * 8 + 2 * p) * 64 + mt * 16 + r16];
            unsigned hi = Xw[(g * 8 + 2 * p + 1) * 64 + mt * 16 + r16];
            tf16[mt][p] = __builtin_bit_cast(__half2, lo | (hi << 16));
        }

    // ---- preload chunk 0 operands into registers ----
    __half2 th[4];
#pragma unroll
    for (int mt = 0; mt < 4; ++mt) {
        unsigned u = Xw[mt * 16 + r16];              // chunk 0 = x row 0
        th[mt] = __builtin_bit_cast(__half2, (u << 16) | u);
    }
    f16x8 Bf[8];
#pragma unroll
    for (int n = 0; n < 8; ++n)
        Bf[n] = *reinterpret_cast<const f16x8*>(&Wb[0][n * 512 + l * 8]);

    // stage(1) drained (read during iter 0), stage(2) stays in flight;
    // lgkm drained (iter 0 restages slot 0 over our preload reads)
    BAR_VM2();

    f32x4 acc[4][8];
#pragma unroll
    for (int mt = 0; mt < 4; ++mt)
#pragma unroll
        for (int n = 0; n < 8; ++n) acc[mt][n] = (f32x4){0.f, 0.f, 0.f, 0.f};

    // ---------------- unified K loop: chunks k = 0..95 ----------------
    // Ring invariant at iter-k entry: slot (k)%3 dead (chunk k in regs),
    // slot (k+1)%3 = chunk k+1 (landed), slot (k+2)%3 = chunk k+2
    // (stage in flight, drained by this iter's end barrier).
    // Iter k: stage chunk k+3 into slot k%3; burst chunk k from regs;
    // prefetch chunk k+1 regs mid-burst; barrier waits vmcnt(2) only.
    int sl_w = 0;   // k % 3
    int sl_r = 1;   // (k+1) % 3
#pragma unroll 1
    for (int k = 0; k < 96; ++k) {
        {
            // clamped tail keeps vmcnt uniform; writes land in dead slots
            const int cs = (k + 3 < 96) ? (k + 3) : 95;
            const char* src = (const char*)wp + (size_t)cs * 8192 +
                              (size_t)(w * 2) * 1024 + (size_t)l * 16;
            __builtin_amdgcn_global_load_lds((const unsigned int*)src,
                (unsigned int*)&Wb[sl_w][(w * 2) * 512], 16, 0, 0);
            __builtin_amdgcn_global_load_lds((const unsigned int*)(src + 1024),
                (unsigned int*)&Wb[sl_w][(w * 2 + 1) * 512], 16, 0, 0);
        }

        const bool pf_th = (k < 95) && (k != 31);
        const ushortT* WbN = Wb[sl_r];   // chunk k+1 (k=95: dead re-read)
        const ushortT* thp = (k + 1 < 32) ? (Xw + (k + 1) * 64)
                                          : (Hw + (k - 31) * 66);

        // Af for chunk k (from registers; th dead afterwards)
        union AfU { __half2 h2[4]; f16x8 v; };
        AfU Af[4];
#pragma unroll
        for (int mt = 0; mt < 4; ++mt)
#pragma unroll
            for (int p = 0; p < 4; ++p)
                Af[mt].h2[p] = __hmul2(tf16[mt][p], th[mt]);

        // prefetch next chunk's th (skipped at layer boundary k==31)
        if (pf_th) {
#pragma unroll
            for (int mt = 0; mt < 4; ++mt) {
                unsigned u = thp[mt * 16 + r16];
                th[mt] = __builtin_bit_cast(__half2, (u << 16) | u);
            }
        }

        // MFMA burst; Bf[n] reloaded from next chunk right after last use
        __builtin_amdgcn_s_setprio(1);
#pragma unroll
        for (int n = 0; n < 8; ++n) {
#pragma unroll
            for (int mt = 0; mt < 4; ++mt)
                acc[mt][n] = __builtin_amdgcn_mfma_f32_16x16x32_f16(
                    Af[mt].v, Bf[n], acc[mt][n], 0, 0, 0);
            Bf[n] = *reinterpret_cast<const f16x8*>(&WbN[n * 512 + l * 8]);
        }
        __builtin_amdgcn_s_setprio(0);

        // counted barrier: drains stage(k+2) (own), leaves stage(k+3) in
        // flight; lgkm drain publishes slot sl_r for iter-(k+1) restage
        BAR_VM2();

        sl_w = sl_r;
        sl_r = (sl_r == 2) ? 0 : sl_r + 1;

        // layer boundary: write hidden table, emit layer-0 direct outputs
        if (k == 31) {
#pragma unroll
            for (int n = 0; n < 4; ++n) {
                float bn = b0[n * 16 + r16];
#pragma unroll
                for (int mt = 0; mt < 4; ++mt)
#pragma unroll
                    for (int r = 0; r < 4; ++r) {
                        float y = fmaxf(acc[mt][n][r] + bn, 0.f);
                        int d = mt * 16 + g * 4 + r;
                        int o = n * 16 + r16;
                        __half hy = __float2half(y);
                        Hw[o * 66 + d] = __builtin_bit_cast(ushortT, hy);
                    }
            }
#pragma unroll
            for (int n = 4; n < 8; ++n) {
                float bn = b0[n * 16 + r16];
                float s = 0.f;
#pragma unroll
                for (int mt = 0; mt < 4; ++mt)
#pragma unroll
                    for (int r = 0; r < 4; ++r)
                        s += fmaxf(acc[mt][n][r] + bn, 0.f);
                s += __shfl_xor(s, 16);
                s += __shfl_xor(s, 32);
                if (l < 16) out[(size_t)b * 192 + (n - 4) * 16 + l] = s;
            }
#pragma unroll
            for (int mt = 0; mt < 4; ++mt)
#pragma unroll
                for (int n = 0; n < 8; ++n) acc[mt][n] = (f32x4){0.f, 0.f, 0.f, 0.f};
            // th for chunk 32 = hidden row 0 (written just above, own wave)
#pragma unroll
            for (int mt = 0; mt < 4; ++mt) {
                unsigned u = Hw[mt * 16 + r16];
                th[mt] = __builtin_bit_cast(__half2, (u << 16) | u);
            }
        }
    }

    // layer-1 epilogue: all 8 n-tiles are direct outputs
#pragma unroll
    for (int n = 0; n < 8; ++n) {
        float bn = b1[n * 16 + r16];
        float s = 0.f;
#pragma unroll
        for (int mt = 0; mt < 4; ++mt)
#pragma unroll
            for (int r = 0; r < 4; ++r)
                s += fmaxf(acc[mt][n][r] + bn, 0.f);
        s += __shfl_xor(s, 16);
        s += __shfl_xor(s, 32);
        if (l < 16) out[(size_t)b * 192 + 64 + n * 16 + l] = s;
    }
}

// ---------- fp32 fallback, used only if ws too small ------
__global__ __launch_bounds__(256, 4) void cin_fp32_kernel(
    const float* __restrict__ x, const float* __restrict__ w0,
    const float* __restrict__ b0, const float* __restrict__ w1,
    const float* __restrict__ b1, float* __restrict__ out)
{
    const int b = blockIdx.x;
    const int tid = threadIdx.x;
    const int d = tid & 63;
    const int wave = tid >> 6;

    __shared__ float Xs[32][64];
    __shared__ float Hsf[64][64];

    const float* xb = x + (size_t)b * 2048;
    float treg[32];
#pragma unroll
    for (int f = 0; f < 32; ++f) treg[f] = xb[f * 64 + d];
    if (wave == 0) {
#pragma unroll
        for (int f = 0; f < 32; ++f) Xs[f][d] = treg[f];
    }
    __syncthreads();
    const int o_base = __builtin_amdgcn_readfirstlane(wave * 32);

    for (int oi = 0; oi < 32; ++oi) {
        const int o = o_base + oi;
        const float* wrow = w0 + (size_t)o * 1024;
        float acc = b0[o];
        for (int h = 0; h < 32; ++h) {
            const float* wv = wrow + h * 32;
            const float th = Xs[h][d];
            float s0 = 0.f, s1 = 0.f, s2 = 0.f, s3 = 0.f;
#pragma unroll
            for (int f = 0; f < 32; f += 4) {
                s0 = fmaf(wv[f + 0], treg[f + 0], s0);
                s1 = fmaf(wv[f + 1], treg[f + 1], s1);
                s2 = fmaf(wv[f + 2], treg[f + 2], s2);
                s3 = fmaf(wv[f + 3], treg[f + 3], s3);
            }
            acc = fmaf((s0 + s1) + (s2 + s3), th, acc);
        }
        float y = fmaxf(acc, 0.f);
        if (o < 64) {
            Hsf[o][d] = y;
        } else {
#pragma unroll
            for (int off = 32; off > 0; off >>= 1) y += __shfl_xor(y, off, 64);
            if (d == 0) out[(size_t)b * 192 + (o - 64)] = y;
        }
    }
    __syncthreads();

    for (int oi = 0; oi < 32; ++oi) {
        const int o = o_base + oi;
        const float* wrow = w1 + (size_t)o * 2048;
        float acc = b1[o];
        for (int h = 0; h < 64; ++h) {
            const float* wv = wrow + h * 32;
            const float th = Hsf[h][d];
            float s0 = 0.f, s1 = 0.f, s2 = 0.f, s3 = 0.f;
#pragma unroll
            for (int f = 0; f < 32; f += 4) {
                s0 = fmaf(wv[f + 0], treg[f + 0], s0);
                s1 = fmaf(wv[f + 1], treg[f + 1], s1);
                s2 = fmaf(wv[f + 2], treg[f + 2], s2);
                s3 = fmaf(wv[f + 3], treg[f + 3], s3);
            }
            acc = fmaf((s0 + s1) + (s2 + s3), th, acc);
        }
        float y = fmaxf(acc, 0.f);
#pragma unroll
        for (int off = 32; off > 0; off >>= 1) y += __shfl_xor(y, off, 64);
        if (d == 0) out[(size_t)b * 192 + 64 + o] = y;
    }
}

extern "C" void kernel_launch(void* const* d_in, const int* in_sizes, int n_in,
                              void* d_out, int out_size, void* d_ws, size_t ws_size,
                              hipStream_t stream) {
    const float* x  = (const float*)d_in[0];
    const float* w0 = (const float*)d_in[1];
    const float* b0 = (const float*)d_in[2];
    const float* w1 = (const float*)d_in[3];
    const float* b1 = (const float*)d_in[4];
    float* out = (float*)d_out;

    if (ws_size >= 786432) {
        ushortT* wp = (ushortT*)d_ws;
        cin_pack_w<<<192, 256, 0, stream>>>(w0, w1, wp);
        cin_mfma_kernel<<<1024, 256, 0, stream>>>(x, b0, b1, wp, out);
    } else {
        cin_fp32_kernel<<<4096, 256, 0, stream>>>(x, w0, b0, w1, b1, out);
    }
}

// Round 3
// 162.523 us; speedup vs baseline: 1.0485x; 1.0485x over previous
//
#include <hip/hip_runtime.h>
#include <hip/hip_fp16.h>

// CIN (xDeepFM), B=4096, F=32, D=64, layers 128/128.
// Per row m=(b,d): t = x[b,:,d] (32 f32)
//   layer0: y0[o] = relu(b0[o] + sum_{h,f} w0[o, h*32+f] t[h] t[f])
//   hidden = y0[0:64]; direct0 = y0[64:128]
//   layer1: y1[o] = relu(b1[o] + sum_{hh,f} w1[o, hh*32+f] hidden[hh] t[f])
//   out[b] = concat(direct0, y1) summed over d  -> (4096, 192) f32
//
// MFMA mapping (v_mfma_f32_16x16x32_f16):
//   A frag: lane holds A[m = l&15][k = (l>>4)*8 + j]
//   B frag: lane holds B[k = (l>>4)*8 + j][n = l&15]
//   C/D   : col = l&15, row = (l>>4)*4 + reg
//
// Round-12: R10 (register pipeline) and R11 (counted vmcnt, 3-deep ring)
// were both NEUTRAL -> neither read latency nor stage-drain latency is
// the bubble. Both held the barrier COUNT constant (96/round). Remaining
// theory: ~880 cyc/phase fixed barrier cost (8-wave arrive/release skew +
// post-barrier issue crunch). Fix: 48 fat phases of 2 chunks each -- one
// barrier per 64 MFMAs instead of per 32. The two chunk bursts inside a
// phase are barrier-free so chunk-1 reads overlap burst 0. LDS shrunk
// 73->64 KB by unioning the x-table (dead after chunk 31) with the
// hidden table (live from chunk 32) in one 8 KB/wave buffer.

typedef __attribute__((ext_vector_type(8))) _Float16 f16x8;
typedef __attribute__((ext_vector_type(4))) float f32x4;
typedef __attribute__((ext_vector_type(4))) unsigned short us4;
typedef unsigned short ushortT;

// ---------- weight pre-pack: f32 -> f16 in B-fragment order ----------
// Stream chunk ktg (8192 B = 4096 ushorts): frag (ktg, n) at ushort
// offset ktg*4096 + n*512 + l*8.
// ktg<32 -> w0 kt=ktg; ktg>=32 -> w1 kt=ktg-32 (contiguous: 32*4096=131072).
__global__ void cin_pack_w(const float* __restrict__ w0,
                           const float* __restrict__ w1,
                           ushortT* __restrict__ wp) {
    int gidx = blockIdx.x * 256 + threadIdx.x;
    if (gidx >= 49152) return;
    const float* src;
    ushortT* dst;
    if (gidx < 16384) {
        int kk = gidx >> 9, rem = gidx & 511;
        int n = rem >> 6, lp = rem & 63;
        int o = n * 16 + (lp & 15);
        int c = kk * 32 + ((lp >> 4) << 3);
        src = w0 + o * 1024 + c;
        dst = wp + gidx * 8;
    } else {
        int g1 = gidx - 16384;
        int kk = g1 >> 9, rem = g1 & 511;
        int n = rem >> 6, lp = rem & 63;
        int o = n * 16 + (lp & 15);
        int c = kk * 32 + ((lp >> 4) << 3);
        src = w1 + o * 2048 + c;
        dst = wp + 131072 + g1 * 8;
    }
    ushortT tmp[8];
#pragma unroll
    for (int j = 0; j < 8; ++j) {
        __half h = __float2half(src[j]);
        tmp[j] = __builtin_bit_cast(ushortT, h);
    }
    *reinterpret_cast<f16x8*>(dst) = *reinterpret_cast<const f16x8*>(tmp);
}

__global__ __launch_bounds__(256, 2) void cin_mfma_kernel(
    const float* __restrict__ x,      // [4096][32][64]
    const float* __restrict__ b0,     // [128]
    const float* __restrict__ b1,     // [128]
    const ushortT* __restrict__ wp,   // packed weights (f16 bits)
    float* __restrict__ out)          // [4096][192]
{
    const int tid = threadIdx.x;
    const int l   = tid & 63;         // lane
    const int w   = tid >> 6;         // wave 0..3 -> b = blockIdx*4 + w
    const int b   = blockIdx.x * 4 + w;
    const int r16 = l & 15;
    const int g   = l >> 4;

    // Union buffer per wave (8 KB): x table rows 0..31 (stride 64) during
    // layer 0, overwritten by hidden rows 0..63 (stride 64) at boundary.
    __shared__ ushortT U[4][4096];                    // 32 KB
    __shared__ __align__(16) ushortT Wb[2][8192];     // pair dbuf (32 KB)

    ushortT* Xw = U[w];    // also Hw after the boundary

    // ---- prologue: x (f32) -> f16 table Xw rows 0..31 (own wave) ----
    const float* xb = x + (size_t)b * 2048;
#pragma unroll
    for (int i = 0; i < 8; ++i) {
        float4 v = reinterpret_cast<const float4*>(xb)[i * 64 + l];
        int flat = (i * 64 + l) * 4;
        us4 h;
        h[0] = __builtin_bit_cast(ushortT, __float2half(v.x));
        h[1] = __builtin_bit_cast(ushortT, __float2half(v.y));
        h[2] = __builtin_bit_cast(ushortT, __float2half(v.z));
        h[3] = __builtin_bit_cast(ushortT, __float2half(v.w));
        *reinterpret_cast<us4*>(&Xw[flat]) = h;
    }

    // ---- stage pair 0 (chunks 0,1 = 16 KB) into slot 0: 4 x 1 KB/wave ----
#pragma unroll
    for (int j = 0; j < 4; ++j) {
        const int seg = w * 4 + j;
        const char* src = (const char*)wp + (size_t)seg * 1024 + (size_t)l * 16;
        __builtin_amdgcn_global_load_lds((const unsigned int*)src,
                                         (unsigned int*)&Wb[0][seg * 512], 16, 0, 0);
    }
    __syncthreads();   // drains vmcnt (pair 0) + lgkm (Xw fill)

    // ---- base T-fragments: tf16[mt][p] = (t[d][g*8+2p], t[d][g*8+2p+1]) ----
    __half2 tf16[4][4];
#pragma unroll
    for (int mt = 0; mt < 4; ++mt)
#pragma unroll
        for (int p = 0; p < 4; ++p) {
            unsigned lo = Xw[(g * 8 + 2 * p) * 64 + mt * 16 + r16];
            unsigned hi = Xw[(g * 8 + 2 * p + 1) * 64 + mt * 16 + r16];
            tf16[mt][p] = __builtin_bit_cast(__half2, lo | (hi << 16));
        }

    f32x4 acc[4][8];
#pragma unroll
    for (int mt = 0; mt < 4; ++mt)
#pragma unroll
        for (int n = 0; n < 8; ++n) acc[mt][n] = (f32x4){0.f, 0.f, 0.f, 0.f};

    union AfU { __half2 h2[4]; f16x8 v; };

    // ---------------- phase loop: 48 phases x 2 chunks ----------------
    // Phase p consumes pair p from slot p&1, stages pair p+1 into the
    // other slot. One barrier per phase (64 MFMAs per barrier).
#pragma unroll 1
    for (int p = 0; p < 48; ++p) {
        const int ps = p & 1;
        const int k0 = 2 * p;

        // stage next pair (issued first; lands during this phase body)
        if (p + 1 < 48) {
#pragma unroll
            for (int j = 0; j < 4; ++j) {
                const int seg = w * 4 + j;
                const char* src = (const char*)wp + (size_t)(p + 1) * 16384 +
                                  (size_t)seg * 1024 + (size_t)l * 16;
                __builtin_amdgcn_global_load_lds((const unsigned int*)src,
                    (unsigned int*)&Wb[ps ^ 1][seg * 512], 16, 0, 0);
            }
        }

        // th for chunk k0 (x rows for k<32, hidden rows for k>=32)
        const ushortT* th0p = Xw + (size_t)((k0 < 32) ? k0 : (k0 - 32)) * 64;
        __half2 th[4];
#pragma unroll
        for (int mt = 0; mt < 4; ++mt) {
            unsigned u = th0p[mt * 16 + r16];
            th[mt] = __builtin_bit_cast(__half2, (u << 16) | u);
        }

        // B-frags for chunk k0
        f16x8 Bf[8];
#pragma unroll
        for (int n = 0; n < 8; ++n)
            Bf[n] = *reinterpret_cast<const f16x8*>(&Wb[ps][n * 512 + l * 8]);

        // Af for chunk k0; then issue chunk-k1 th reads (th regs now free)
        AfU Af[4];
#pragma unroll
        for (int mt = 0; mt < 4; ++mt)
#pragma unroll
            for (int q = 0; q < 4; ++q)
                Af[mt].h2[q] = __hmul2(tf16[mt][q], th[mt]);

        const int k1 = k0 + 1;
        const ushortT* th1p = Xw + (size_t)((k1 < 32) ? k1 : (k1 - 32)) * 64;
#pragma unroll
        for (int mt = 0; mt < 4; ++mt) {
            unsigned u = th1p[mt * 16 + r16];
            th[mt] = __builtin_bit_cast(__half2, (u << 16) | u);
        }

        // burst 0; Bf[n] reloaded for chunk k1 right after last use
        __builtin_amdgcn_s_setprio(1);
#pragma unroll
        for (int n = 0; n < 8; ++n) {
#pragma unroll
            for (int mt = 0; mt < 4; ++mt)
                acc[mt][n] = __builtin_amdgcn_mfma_f32_16x16x32_f16(
                    Af[mt].v, Bf[n], acc[mt][n], 0, 0, 0);
            Bf[n] = *reinterpret_cast<const f16x8*>(&Wb[ps][4096 + n * 512 + l * 8]);
        }
        __builtin_amdgcn_s_setprio(0);

        // Af for chunk k1 (th landed during burst 0)
#pragma unroll
        for (int mt = 0; mt < 4; ++mt)
#pragma unroll
            for (int q = 0; q < 4; ++q)
                Af[mt].h2[q] = __hmul2(tf16[mt][q], th[mt]);

        // burst 1
        __builtin_amdgcn_s_setprio(1);
#pragma unroll
        for (int n = 0; n < 8; ++n)
#pragma unroll
            for (int mt = 0; mt < 4; ++mt)
                acc[mt][n] = __builtin_amdgcn_mfma_f32_16x16x32_f16(
                    Af[mt].v, Bf[n], acc[mt][n], 0, 0, 0);
        __builtin_amdgcn_s_setprio(0);

        __syncthreads();   // pair p+1 landed; all reads of slot ps done

        // layer boundary after phase 15 (chunks 30,31 complete layer 0)
        if (p == 15) {
            ushortT* Hw = Xw;   // union: x rows dead from here on
#pragma unroll
            for (int n = 0; n < 4; ++n) {
                float bn = b0[n * 16 + r16];
#pragma unroll
                for (int mt = 0; mt < 4; ++mt) {
                    us4 hv;
#pragma unroll
                    for (int r = 0; r < 4; ++r) {
                        float y = fmaxf(acc[mt][n][r] + bn, 0.f);
                        hv[r] = __builtin_bit_cast(ushortT, __float2half(y));
                    }
                    const int o = n * 16 + r16;
                    *reinterpret_cast<us4*>(&Hw[o * 64 + mt * 16 + g * 4]) = hv;
                }
            }
#pragma unroll
            for (int n = 4; n < 8; ++n) {
                float bn = b0[n * 16 + r16];
                float s = 0.f;
#pragma unroll
                for (int mt = 0; mt < 4; ++mt)
#pragma unroll
                    for (int r = 0; r < 4; ++r)
                        s += fmaxf(acc[mt][n][r] + bn, 0.f);
                s += __shfl_xor(s, 16);
                s += __shfl_xor(s, 32);
                if (l < 16) out[(size_t)b * 192 + (n - 4) * 16 + l] = s;
            }
#pragma unroll
            for (int mt = 0; mt < 4; ++mt)
#pragma unroll
                for (int n = 0; n < 8; ++n) acc[mt][n] = (f32x4){0.f, 0.f, 0.f, 0.f};
        }
    }

    // layer-1 epilogue: all 8 n-tiles are direct outputs
#pragma unroll
    for (int n = 0; n < 8; ++n) {
        float bn = b1[n * 16 + r16];
        float s = 0.f;
#pragma unroll
        for (int mt = 0; mt < 4; ++mt)
#pragma unroll
            for (int r = 0; r < 4; ++r)
                s += fmaxf(acc[mt][n][r] + bn, 0.f);
        s += __shfl_xor(s, 16);
        s += __shfl_xor(s, 32);
        if (l < 16) out[(size_t)b * 192 + 64 + n * 16 + l] = s;
    }
}

// ---------- fp32 fallback, used only if ws too small ------
__global__ __launch_bounds__(256, 4) void cin_fp32_kernel(
    const float* __restrict__ x, const float* __restrict__ w0,
    const float* __restrict__ b0, const float* __restrict__ w1,
    const float* __restrict__ b1, float* __restrict__ out)
{
    const int b = blockIdx.x;
    const int tid = threadIdx.x;
    const int d = tid & 63;
    const int wave = tid >> 6;

    __shared__ float Xs[32][64];
    __shared__ float Hsf[64][64];

    const float* xb = x + (size_t)b * 2048;
    float treg[32];
#pragma unroll
    for (int f = 0; f < 32; ++f) treg[f] = xb[f * 64 + d];
    if (wave == 0) {
#pragma unroll
        for (int f = 0; f < 32; ++f) Xs[f][d] = treg[f];
    }
    __syncthreads();
    const int o_base = __builtin_amdgcn_readfirstlane(wave * 32);

    for (int oi = 0; oi < 32; ++oi) {
        const int o = o_base + oi;
        const float* wrow = w0 + (size_t)o * 1024;
        float acc = b0[o];
        for (int h = 0; h < 32; ++h) {
            const float* wv = wrow + h * 32;
            const float th = Xs[h][d];
            float s0 = 0.f, s1 = 0.f, s2 = 0.f, s3 = 0.f;
#pragma unroll
            for (int f = 0; f < 32; f += 4) {
                s0 = fmaf(wv[f + 0], treg[f + 0], s0);
                s1 = fmaf(wv[f + 1], treg[f + 1], s1);
                s2 = fmaf(wv[f + 2], treg[f + 2], s2);
                s3 = fmaf(wv[f + 3], treg[f + 3], s3);
            }
            acc = fmaf((s0 + s1) + (s2 + s3), th, acc);
        }
        float y = fmaxf(acc, 0.f);
        if (o < 64) {
            Hsf[o][d] = y;
        } else {
#pragma unroll
            for (int off = 32; off > 0; off >>= 1) y += __shfl_xor(y, off, 64);
            if (d == 0) out[(size_t)b * 192 + (o - 64)] = y;
        }
    }
    __syncthreads();

    for (int oi = 0; oi < 32; ++oi) {
        const int o = o_base + oi;
        const float* wrow = w1 + (size_t)o * 2048;
        float acc = b1[o];
        for (int h = 0; h < 64; ++h) {
            const float* wv = wrow + h * 32;
            const float th = Hsf[h][d];
            float s0 = 0.f, s1 = 0.f, s2 = 0.f, s3 = 0.f;
#pragma unroll
            for (int f = 0; f < 32; f += 4) {
                s0 = fmaf(wv[f + 0], treg[f + 0], s0);
                s1 = fmaf(wv[f + 1], treg[f + 1], s1);
                s2 = fmaf(wv[f + 2], treg[f + 2], s2);
                s3 = fmaf(wv[f + 3], treg[f + 3], s3);
            }
            acc = fmaf((s0 + s1) + (s2 + s3), th, acc);
        }
        float y = fmaxf(acc, 0.f);
#pragma unroll
        for (int off = 32; off > 0; off >>= 1) y += __shfl_xor(y, off, 64);
        if (d == 0) out[(size_t)b * 192 + 64 + o] = y;
    }
}

extern "C" void kernel_launch(void* const* d_in, const int* in_sizes, int n_in,
                              void* d_out, int out_size, void* d_ws, size_t ws_size,
                              hipStream_t stream) {
    const float* x  = (const float*)d_in[0];
    const float* w0 = (const float*)d_in[1];
    const float* b0 = (const float*)d_in[2];
    const float* w1 = (const float*)d_in[3];
    const float* b1 = (const float*)d_in[4];
    float* out = (float*)d_out;

    if (ws_size >= 786432) {
        ushortT* wp = (ushortT*)d_ws;
        cin_pack_w<<<192, 256, 0, stream>>>(w0, w1, wp);
        cin_mfma_kernel<<<1024, 256, 0, stream>>>(x, b0, b1, wp, out);
    } else {
        cin_fp32_kernel<<<4096, 256, 0, stream>>>(x, w0, b0, w1, b1, out);
    }
}